// Round 1
// baseline (178.751 us; speedup 1.0000x reference)
//
#include <hip/hip_runtime.h>

#define ALPHA 0.2f
#define NEG_INF -9e15f

// N=20000, K=32, d=128, R=100, S=4 (K,d,S hardcoded; N,R passed)
__global__ __launch_bounds__(256, 3)
void gat_fused_kernel(const float* __restrict__ item,
                      const float* __restrict__ ent,
                      const float* __restrict__ rel,
                      const int*   __restrict__ rel_ids,
                      const int*   __restrict__ adj,
                      const float* __restrict__ fc_w,
                      const float* __restrict__ fc_b,
                      const float* __restrict__ out_w,
                      const float* __restrict__ out_b,
                      const float* __restrict__ probs,
                      float* __restrict__ out,
                      int N, int R)
{
    __shared__ __align__(16) float prod[32 * 128];   // rel*ent products, 16 KB
    __shared__ __align__(16) float item_lds[128];
    __shared__ __align__(16) float y_lds[128];
    __shared__ float e_red[32];
    __shared__ float w_lds[32];
    __shared__ float dpart[128];
    __shared__ float sitem_part[2];
    __shared__ float asum[256];                      // row-sums of rel_dom_probs

    const int t  = threadIdx.x;
    const int k  = t >> 3;      // neighbor index 0..31
    const int r  = t & 7;       // d-slice index 0..7
    const int j  = t & 127;     // output feature
    const int dh = t >> 7;      // d-half for phase D

    // ---------------- block-start staging (amortized over ~10 nodes) --------
    // out_w rows in registers: thread t owns W[j][dh*64 .. dh*64+63]
    float4 w4[16];
    #pragma unroll
    for (int i = 0; i < 16; ++i)
        w4[i] = *(const float4*)&out_w[(size_t)j * 128 + dh * 64 + i * 4];

    // fc_w slices for this thread's (r) d-positions
    float4 fr[4], fe[4];
    #pragma unroll
    for (int c = 0; c < 4; ++c) {
        fr[c] = *(const float4*)&fc_w[128 + c * 32 + r * 4];
        fe[c] = *(const float4*)&fc_w[256 + c * 32 + r * 4];
    }
    const float fcw_item = (t < 128) ? fc_w[t] : 0.0f;
    const float outb     = (t < 128) ? out_b[j] : 0.0f;
    const float fcb      = fc_b[0];
    if (t < R && t < 256) {
        float4 q = *(const float4*)&probs[t * 4];
        asum[t] = q.x + q.y + q.z + q.w;
    }
    __syncthreads();

    for (int n = blockIdx.x; n < N; n += gridDim.x) {
        const size_t base = (size_t)n * 4096;

        // prefetch phase-B operands (consumed after barrier -> latency hidden)
        int maskv = 0, idv = 0;
        if (t < 32) {
            maskv = adj[(size_t)n * 32 + t];
            idv   = rel_ids[(size_t)n * 32 + t];
        }

        // ---------------- Phase A: load rel/ent once, products -> LDS -------
        float4 rv[4], ev[4];
        const float* rp = rel + base + k * 128 + r * 4;
        const float* ep = ent + base + k * 128 + r * 4;
        #pragma unroll
        for (int c = 0; c < 4; ++c) {
            rv[c] = *(const float4*)(rp + c * 32);
            ev[c] = *(const float4*)(ep + c * 32);
        }
        float epart = 0.0f;
        #pragma unroll
        for (int c = 0; c < 4; ++c) {
            float4 p;
            p.x = rv[c].x * ev[c].x;
            p.y = rv[c].y * ev[c].y;
            p.z = rv[c].z * ev[c].z;
            p.w = rv[c].w * ev[c].w;
            *(float4*)&prod[k * 128 + c * 32 + r * 4] = p;
            epart += rv[c].x * fr[c].x + rv[c].y * fr[c].y
                   + rv[c].z * fr[c].z + rv[c].w * fr[c].w;
            epart += ev[c].x * fe[c].x + ev[c].y * fe[c].y
                   + ev[c].z * fe[c].z + ev[c].w * fe[c].w;
        }
        // item dot + stash item row
        if (t < 128) {
            float iv = item[(size_t)n * 128 + t];
            item_lds[t] = iv;
            float s = iv * fcw_item;
            #pragma unroll
            for (int m = 1; m < 64; m <<= 1) s += __shfl_xor(s, m, 64);
            if ((t & 63) == 0) sitem_part[t >> 6] = s;
        }
        // reduce e over the 8 d-slices (contiguous lanes, width-8 butterfly)
        epart += __shfl_xor(epart, 1, 8);
        epart += __shfl_xor(epart, 2, 8);
        epart += __shfl_xor(epart, 4, 8);
        if (r == 0) e_red[k] = epart;
        __syncthreads();

        // ---------------- Phase B: masked softmax over K (lanes 0..31) ------
        if (t < 32) {
            float e = e_red[t] + sitem_part[0] + sitem_part[1] + fcb;
            e = (e > 0.0f) ? e : ALPHA * e;                 // LeakyReLU
            float m = (maskv > 0) ? e : NEG_INF;            // mask
            float mx = m;
            #pragma unroll
            for (int s = 16; s >= 1; s >>= 1) mx = fmaxf(mx, __shfl_xor(mx, s, 32));
            float p = __expf(m - mx);
            float ps = p;
            #pragma unroll
            for (int s = 16; s >= 1; s >>= 1) ps += __shfl_xor(ps, s, 32);
            float pi = p / ps;
            float a  = (idv >= 0 && idv < R) ? asum[idv] : 0.0f;
            w_lds[t] = pi * a;
        }
        __syncthreads();

        // ---------------- Phase C: agg over k, + residual --------------------
        if (t < 128) {
            float s = 0.0f;
            #pragma unroll
            for (int kk = 0; kk < 32; ++kk)
                s = fmaf(w_lds[kk], prod[kk * 128 + t], s);  // bank = t%32, clean
            y_lds[t] = s + item_lds[t];
        }
        __syncthreads();

        // ---------------- Phase D: out = relu(y @ W^T + b) -------------------
        float acc = 0.0f;
        #pragma unroll
        for (int i = 0; i < 16; ++i) {
            float4 y4 = *(const float4*)&y_lds[dh * 64 + i * 4];  // LDS broadcast
            acc += w4[i].x * y4.x + w4[i].y * y4.y
                 + w4[i].z * y4.z + w4[i].w * y4.w;
        }
        if (dh == 1) dpart[j] = acc;
        __syncthreads();
        if (t < 128) {
            float o = acc + dpart[j] + outb;
            out[(size_t)n * 128 + j] = fmaxf(o, 0.0f);
        }
    }
}

extern "C" void kernel_launch(void* const* d_in, const int* in_sizes, int n_in,
                              void* d_out, int out_size, void* d_ws, size_t ws_size,
                              hipStream_t stream) {
    const float* item    = (const float*)d_in[0];
    const float* ent     = (const float*)d_in[1];
    const float* rel     = (const float*)d_in[2];
    const int*   rel_ids = (const int*)  d_in[3];
    const int*   adj     = (const int*)  d_in[4];
    const float* fc_w    = (const float*)d_in[5];
    const float* fc_b    = (const float*)d_in[6];
    const float* out_w   = (const float*)d_in[7];
    const float* out_b   = (const float*)d_in[8];
    const float* probs   = (const float*)d_in[9];
    float* out = (float*)d_out;

    const int N = in_sizes[0] / 128;   // 20000
    const int R = in_sizes[9] / 4;     // 100

    int blocks = 2048;
    if (blocks > N) blocks = N;
    hipLaunchKernelGGL(gat_fused_kernel, dim3(blocks), dim3(256), 0, stream,
                       item, ent, rel, rel_ids, adj, fc_w, fc_b,
                       out_w, out_b, probs, out, N, R);
}

// Round 2
// 173.549 us; speedup vs baseline: 1.0300x; 1.0300x over previous
//
#include <hip/hip_runtime.h>

#define ALPHA 0.2f
#define NEG_INF -9e15f

__device__ __forceinline__ void block_bar() {
    // raw barrier: drain LDS ops (cross-wave visibility) but leave global
    // prefetch loads in flight (avoid the __syncthreads vmcnt(0) drain)
    asm volatile("s_waitcnt lgkmcnt(0)" ::: "memory");
    __builtin_amdgcn_s_barrier();
}

__device__ __forceinline__ float dot4(float4 a, float4 b) {
    return a.x * b.x + a.y * b.y + a.z * b.z + a.w * b.w;
}

// K1: attention + aggregation + residual -> y (written to d_out)
__global__ __launch_bounds__(256, 4)
void gat_k1(const float* __restrict__ item,
            const float* __restrict__ ent,
            const float* __restrict__ rel,
            const int*   __restrict__ rel_ids,
            const int*   __restrict__ adj,
            const float* __restrict__ fc_w,
            const float* __restrict__ fc_b,
            const float* __restrict__ probs,
            float* __restrict__ y,
            int N, int R)
{
    __shared__ __align__(16) float prod[2][4096];  // rel*ent, double-buffered
    __shared__ float e_red[32];
    __shared__ float w_lds[32];
    __shared__ float sitem[2];
    __shared__ float asum[128];

    const int t = threadIdx.x;
    const int k = t >> 3, r = t & 7;
    const int base_off = k * 128 + r * 4;

    float4 fr[4], fe[4];
    #pragma unroll
    for (int c = 0; c < 4; ++c) {
        fr[c] = *(const float4*)&fc_w[128 + c * 32 + r * 4];
        fe[c] = *(const float4*)&fc_w[256 + c * 32 + r * 4];
    }
    const float fcw_i = (t < 128) ? fc_w[t] : 0.0f;
    const float fcb   = fc_b[0];
    if (t < R) {
        float4 q = *(const float4*)&probs[t * 4];
        asum[t] = q.x + q.y + q.z + q.w;
    }

    const int stride = gridDim.x;

    // prologue prefetch (node blockIdx.x)
    float4 pr[4], pe[4];
    float iv_p = 0.0f;
    int mv_p = 0, id_p = 0;
    {
        const float* rp  = rel + (size_t)blockIdx.x * 4096 + base_off;
        const float* epp = ent + (size_t)blockIdx.x * 4096 + base_off;
        #pragma unroll
        for (int c = 0; c < 4; ++c) {
            pr[c] = *(const float4*)(rp  + c * 32);
            pe[c] = *(const float4*)(epp + c * 32);
        }
        if (t < 128) iv_p = item[(size_t)blockIdx.x * 128 + t];
        if (t < 32) {
            mv_p = adj[(size_t)blockIdx.x * 32 + t];
            id_p = rel_ids[(size_t)blockIdx.x * 32 + t];
        }
    }

    int par = 0;
    for (int n = blockIdx.x; n < N; n += stride) {
        const float ivc = iv_p;
        const int mvc = mv_p, idc = id_p;

        // ---- Phase A: consume prefetched regs -> products + e-partials ----
        float epa = 0.0f;
        float* pb = &prod[par][base_off];
        #pragma unroll
        for (int c = 0; c < 4; ++c) {
            float4 p;
            p.x = pr[c].x * pe[c].x;
            p.y = pr[c].y * pe[c].y;
            p.z = pr[c].z * pe[c].z;
            p.w = pr[c].w * pe[c].w;
            *(float4*)(pb + c * 32) = p;
            epa += dot4(pr[c], fr[c]) + dot4(pe[c], fe[c]);
        }

        // ---- issue next node's loads (stay in flight across barriers) ----
        int np = n + stride; if (np >= N) np = n;
        {
            const float* rp  = rel + (size_t)np * 4096 + base_off;
            const float* epp = ent + (size_t)np * 4096 + base_off;
            #pragma unroll
            for (int c = 0; c < 4; ++c) {
                pr[c] = *(const float4*)(rp  + c * 32);
                pe[c] = *(const float4*)(epp + c * 32);
            }
            if (t < 128) iv_p = item[(size_t)np * 128 + t];
            if (t < 32) {
                mv_p = adj[(size_t)np * 32 + t];
                id_p = rel_ids[(size_t)np * 32 + t];
            }
        }

        // reduce e over the 8 d-slices
        epa += __shfl_xor(epa, 1, 8);
        epa += __shfl_xor(epa, 2, 8);
        epa += __shfl_xor(epa, 4, 8);
        if (r == 0) e_red[k] = epa;
        // item dot
        if (t < 128) {
            float s = ivc * fcw_i;
            #pragma unroll
            for (int m = 1; m < 64; m <<= 1) s += __shfl_xor(s, m, 64);
            if ((t & 63) == 0) sitem[t >> 6] = s;
        }
        block_bar();

        // ---- Phase B: masked softmax over K ----
        if (t < 32) {
            float e = e_red[t] + sitem[0] + sitem[1] + fcb;
            e = (e > 0.0f) ? e : ALPHA * e;
            float m = (mvc > 0) ? e : NEG_INF;
            float mx = m;
            #pragma unroll
            for (int s2 = 16; s2 >= 1; s2 >>= 1) mx = fmaxf(mx, __shfl_xor(mx, s2, 32));
            float p = __expf(m - mx);
            float ps = p;
            #pragma unroll
            for (int s2 = 16; s2 >= 1; s2 >>= 1) ps += __shfl_xor(ps, s2, 32);
            float a = (idc >= 0 && idc < R) ? asum[idc] : 0.0f;
            w_lds[t] = (p / ps) * a;
        }
        block_bar();

        // ---- Phase C: aggregate + residual -> y ----
        if (t < 128) {
            float s = 0.0f;
            const float* pp = &prod[par][t];
            #pragma unroll
            for (int kk = 0; kk < 32; ++kk) s = fmaf(w_lds[kk], pp[kk * 128], s);
            y[(size_t)n * 128 + t] = s + ivc;
        }
        par ^= 1;
    }
}

// K2: out = relu(y @ W^T + b), in place on d_out.
// thread t: d-chunk c = t&7 (16 floats), j-group g = t>>3 (4 features)
__global__ __launch_bounds__(256, 4)
void gat_k2(const float* __restrict__ out_w,
            const float* __restrict__ out_b,
            float* __restrict__ y, int N)
{
    __shared__ __align__(16) float ylds[128];
    __shared__ __align__(16) float plds[1024];   // [4 a][32 g][8 c]

    const int t = threadIdx.x;
    const int c = t & 7;
    const int g = t >> 3;

    float4 w4[16];   // W[4g+a][c*16 + i*4 ..], a<4, i<4 -> stays in regs
    #pragma unroll
    for (int a = 0; a < 4; ++a)
        #pragma unroll
        for (int i = 0; i < 4; ++i)
            w4[a * 4 + i] = *(const float4*)&out_w[(size_t)(g * 4 + a) * 128 + c * 16 + i * 4];
    const float bj = out_b[t & 127];
    const int stride = gridDim.x;

    float vcur = 0.0f;
    if (t < 128) vcur = y[(size_t)blockIdx.x * 128 + t];

    for (int n = blockIdx.x; n < N; n += stride) {
        if (t < 128) ylds[t] = vcur;
        block_bar();
        // prefetch next row (overlaps compute; unused garbage on last iter)
        int np = n + stride; if (np >= N) np = n;
        float vn = 0.0f;
        if (t < 128) vn = y[(size_t)np * 128 + t];

        float4 yc[4];
        #pragma unroll
        for (int i = 0; i < 4; ++i) yc[i] = *(const float4*)&ylds[c * 16 + i * 4];
        #pragma unroll
        for (int a = 0; a < 4; ++a) {
            float s = 0.0f;
            #pragma unroll
            for (int i = 0; i < 4; ++i) s += dot4(w4[a * 4 + i], yc[i]);
            plds[a * 256 + g * 8 + c] = s;
        }
        block_bar();
        if (t < 128) {
            const int j = t, a2 = j & 3, g2 = j >> 2;
            const float* pp = &plds[a2 * 256 + g2 * 8];
            float4 u0 = *(const float4*)pp;
            float4 u1 = *(const float4*)(pp + 4);
            float s = u0.x + u0.y + u0.z + u0.w + u1.x + u1.y + u1.z + u1.w + bj;
            y[(size_t)n * 128 + j] = fmaxf(s, 0.0f);
        }
        vcur = vn;
    }
}

extern "C" void kernel_launch(void* const* d_in, const int* in_sizes, int n_in,
                              void* d_out, int out_size, void* d_ws, size_t ws_size,
                              hipStream_t stream) {
    const float* item    = (const float*)d_in[0];
    const float* ent     = (const float*)d_in[1];
    const float* rel     = (const float*)d_in[2];
    const int*   rel_ids = (const int*)  d_in[3];
    const int*   adj     = (const int*)  d_in[4];
    const float* fc_w    = (const float*)d_in[5];
    const float* fc_b    = (const float*)d_in[6];
    const float* out_w   = (const float*)d_in[7];
    const float* out_b   = (const float*)d_in[8];
    const float* probs   = (const float*)d_in[9];
    float* out = (float*)d_out;

    const int N = in_sizes[0] / 128;   // 20000
    const int R = in_sizes[9] / 4;     // 100

    int blocks1 = 2048; if (blocks1 > N) blocks1 = N;
    hipLaunchKernelGGL(gat_k1, dim3(blocks1), dim3(256), 0, stream,
                       item, ent, rel, rel_ids, adj, fc_w, fc_b, probs, out, N, R);

    int blocks2 = 2048; if (blocks2 > N) blocks2 = N;
    hipLaunchKernelGGL(gat_k2, dim3(blocks2), dim3(256), 0, stream,
                       out_w, out_b, out, N);
}